// Round 2
// baseline (9079.394 us; speedup 1.0000x reference)
//
#include <hip/hip_runtime.h>
#include <math.h>

#define SEQ 2048
#define DIM 2048
#define NH 16
#define HD 128
#define CACHEB 408
#define RECENT 204
#define PEN 0.4f
#define QK_SCALE 0.08838834764831845f  // 1/sqrt(128)

// ---------------- generic f32 GEMM: C = scale * A(MxK) * B(NxK)^T ----------
// 64x64 tile, 256 threads, 4x4 per thread, BK=16.
__global__ __launch_bounds__(256)
void gemm_nt(const float* __restrict__ A, const float* __restrict__ B,
             float* __restrict__ C, int M, int N, int K,
             int lda, int ldb, int ldc,
             long aBatch, long bBatch, long cBatch,
             float scale, int causal, int trunc_a)
{
    A += (long)blockIdx.z * aBatch;
    B += (long)blockIdx.z * bBatch;
    C += (long)blockIdx.z * cBatch;
    int m0 = blockIdx.y * 64, n0 = blockIdx.x * 64;
    if (causal && n0 > m0 + 63) return;           // tile entirely above diagonal
    int Keff = trunc_a ? min(K, m0 + 64) : K;     // A rows are zero past diag (probs)

    __shared__ float As[16][64];
    __shared__ float Bs[16][64];
    int tid = threadIdx.x;
    int tx = tid & 15, ty = tid >> 4;
    int lrow = tid >> 2;           // 0..63
    int lcol = (tid & 3) << 2;     // 0,4,8,12
    float acc[4][4] = {};

    for (int k0 = 0; k0 < Keff; k0 += 16) {
        float4 a4 = *(const float4*)(A + (size_t)(m0 + lrow) * lda + k0 + lcol);
        float4 b4 = *(const float4*)(B + (size_t)(n0 + lrow) * ldb + k0 + lcol);
        __syncthreads();
        As[lcol+0][lrow]=a4.x; As[lcol+1][lrow]=a4.y; As[lcol+2][lrow]=a4.z; As[lcol+3][lrow]=a4.w;
        Bs[lcol+0][lrow]=b4.x; Bs[lcol+1][lrow]=b4.y; Bs[lcol+2][lrow]=b4.z; Bs[lcol+3][lrow]=b4.w;
        __syncthreads();
        #pragma unroll
        for (int kk = 0; kk < 16; kk++) {
            float4 av = *(const float4*)&As[kk][ty*4];
            float4 bv = *(const float4*)&Bs[kk][tx*4];
            float a_[4] = {av.x, av.y, av.z, av.w};
            float b_[4] = {bv.x, bv.y, bv.z, bv.w};
            #pragma unroll
            for (int i = 0; i < 4; i++)
                #pragma unroll
                for (int j = 0; j < 4; j++)
                    acc[i][j] = fmaf(a_[i], b_[j], acc[i][j]);
        }
    }
    #pragma unroll
    for (int i = 0; i < 4; i++) {
        float4 o;
        o.x = acc[i][0]*scale; o.y = acc[i][1]*scale;
        o.z = acc[i][2]*scale; o.w = acc[i][3]*scale;
        *(float4*)(C + (size_t)(m0 + ty*4 + i) * ldc + n0 + tx*4) = o;
    }
}

// ---------------- RoPE in place on Q and K --------------------------------
// grid (SEQ, NH/4), block 256: lane i in [0,64) handles dims i and i+64 of head h.
__global__ __launch_bounds__(256)
void rope_qk(float* __restrict__ Q, float* __restrict__ K, const int* __restrict__ pos_ids)
{
    int s = blockIdx.x;
    int i = threadIdx.x & 63;
    int h = blockIdx.y * 4 + (threadIdx.x >> 6);
    double p = (double)pos_ids[s];
    double invf = exp(-((double)(2 * i) / (double)HD) * 9.210340371976184); // ln(10000)
    double ang = p * invf;
    float c = (float)cos(ang), sn = (float)sin(ang);
    size_t b = (size_t)s * DIM + (size_t)h * HD;
    float q0 = Q[b + i], q1 = Q[b + i + 64];
    Q[b + i]      = q0 * c - q1 * sn;
    Q[b + i + 64] = q1 * c + q0 * sn;
    float k0 = K[b + i], k1 = K[b + i + 64];
    K[b + i]      = k0 * c - k1 * sn;
    K[b + i + 64] = k1 * c + k0 * sn;
}

// ---------------- V -> Vt[h][hd][s] ---------------------------------------
__global__ __launch_bounds__(1024)
void transpose_v(const float* __restrict__ V, float* __restrict__ Vt)
{
    __shared__ float tile[32][33];
    int h = blockIdx.z;
    int j0 = blockIdx.x * 32, d0 = blockIdx.y * 32;
    int tx = threadIdx.x, ty = threadIdx.y;
    tile[ty][tx] = V[(size_t)(j0 + ty) * DIM + (size_t)h * HD + d0 + tx];
    __syncthreads();
    Vt[(size_t)h * HD * SEQ + (size_t)(d0 + ty) * SEQ + j0 + tx] = tile[tx][ty];
}

// ---------------- row softmax (causal) in place on Sc ---------------------
// grid (SEQ, g), block 256. Row r: softmax over j<=r; zero j>r.
__global__ __launch_bounds__(256)
void softmax_rows(float* __restrict__ Sc)
{
    int r = blockIdx.x, h = blockIdx.y;
    float* row = Sc + ((size_t)h * SEQ + r) * SEQ;
    int n = r + 1;
    __shared__ float red[256];
    int tid = threadIdx.x;
    float mx = -INFINITY;
    for (int j = tid; j < n; j += 256) mx = fmaxf(mx, row[j]);
    red[tid] = mx; __syncthreads();
    for (int s = 128; s; s >>= 1) { if (tid < s) red[tid] = fmaxf(red[tid], red[tid + s]); __syncthreads(); }
    mx = red[0]; __syncthreads();
    float sum = 0.f;
    for (int j = tid; j < n; j += 256) { float e = expf(row[j] - mx); row[j] = e; sum += e; }
    red[tid] = sum; __syncthreads();
    for (int s = 128; s; s >>= 1) { if (tid < s) red[tid] += red[tid + s]; __syncthreads(); }
    float inv = 1.f / red[0];
    for (int j = tid; j < n; j += 256) row[j] *= inv;
    for (int j = n + tid; j < SEQ; j += 256) row[j] = 0.f;
}

// ---------------- H2O greedy eviction scan --------------------------------
// One wave per head. Lane l owns columns {i*64+l : i in [0,32)}.
// Overwrites Sc rows CACHEB..SEQ-1 in place with the final (masked, renormalized)
// probabilities; rows < CACHEB already equal their final probs.
__global__ __launch_bounds__(64)
void h2o_scan(float* __restrict__ Sc)
{
    int h = blockIdx.x;
    int l = threadIdx.x;
    float* Sh = Sc + (size_t)h * SEQ * SEQ;

    float sel[32];
    #pragma unroll
    for (int i = 0; i < 32; i++) sel[i] = 0.f;

    float buf[32];
    #pragma unroll
    for (int i = 0; i < 32; i++) buf[i] = Sh[i * 64 + l];   // row 0

    // warmup: select0 = sum_t PEN^(CACHEB-1-t) * scores[t]  (Horner)
    for (int t = 0; t < CACHEB; t++) {
        float cur[32];
        #pragma unroll
        for (int i = 0; i < 32; i++) cur[i] = buf[i];
        const float* nr = Sh + (size_t)(t + 1) * SEQ;       // t+1 <= CACHEB < SEQ
        #pragma unroll
        for (int i = 0; i < 32; i++) buf[i] = nr[i * 64 + l];
        #pragma unroll
        for (int i = 0; i < 32; i++) sel[i] = PEN * sel[i] + cur[i];
    }

    unsigned mask = 0xffffffffu;   // bit i: column i*64+l alive
    for (int t = CACHEB; t < SEQ; t++) {
        float* row = Sh + (size_t)t * SEQ;
        float cs[32]; float part = 0.f;
        #pragma unroll
        for (int i = 0; i < 32; i++) {
            float v = ((mask >> i) & 1u) ? buf[i] : 0.f;
            cs[i] = v; part += v;
        }
        if (t + 1 < SEQ) {                                  // prefetch next row
            const float* nr = Sh + (size_t)(t + 1) * SEQ;
            #pragma unroll
            for (int i = 0; i < 32; i++) buf[i] = nr[i * 64 + l];
        }
        #pragma unroll
        for (int off = 32; off; off >>= 1) part += __shfl_xor(part, off, 64);
        float inv = 1.f / part;

        float best = INFINITY; int bpos = SEQ;
        int lim = t - RECENT;
        #pragma unroll
        for (int i = 0; i < 32; i++) {
            float c = cs[i] * inv;
            row[i * 64 + l] = c;                            // final probs for row t
            float s2 = PEN * sel[i] + c;
            sel[i] = s2;
            int p = i * 64 + l;
            bool cand = ((mask >> i) & 1u) && (p <= lim);
            if (cand && s2 < best) { best = s2; bpos = p; } // strict < => first index
        }
        if (t == SEQ - 1) break;                            // last row: no eviction
        #pragma unroll
        for (int off = 32; off; off >>= 1) {
            float ob = __shfl_xor(best, off, 64);
            int   op = __shfl_xor(bpos, off, 64);
            if (ob < best || (ob == best && op < bpos)) { best = ob; bpos = op; }
        }
        if ((bpos & 63) == l) mask &= ~(1u << (bpos >> 6));
    }
}

extern "C" void kernel_launch(void* const* d_in, const int* in_sizes, int n_in,
                              void* d_out, int out_size, void* d_ws, size_t ws_size,
                              hipStream_t stream)
{
    const float* hidden = (const float*)d_in[0];
    const int*   pos    = (const int*)d_in[2];
    const float* wq     = (const float*)d_in[3];
    const float* wk     = (const float*)d_in[4];
    const float* wv     = (const float*)d_in[5];
    const float* wo     = (const float*)d_in[6];
    float* out = (float*)d_out;

    float* ws = (float*)d_ws;
    const size_t SD = (size_t)SEQ * DIM;
    float* Q  = ws;            // 16 MB
    float* K  = ws + SD;       // 16 MB
    float* V  = ws + 2 * SD;   // 16 MB; reused as O after transpose_v
    float* Vt = ws + 3 * SD;   // 16 MB
    float* O  = V;             // alias: V is dead once Vt exists
    float* Sc = ws + 4 * SD;   // up to g * SEQ*SEQ floats

    // Adaptive head-group size: fixed 64 MB + g*16 MB must fit in ws_size.
    const size_t fixedB   = 4 * SD * sizeof(float);
    const size_t perHeadB = (size_t)SEQ * SEQ * sizeof(float);
    int g = NH;
    while (g > 1 && fixedB + (size_t)g * perHeadB > ws_size) g >>= 1;

    // 1. projections: X @ W^T
    gemm_nt<<<dim3(32, 32, 1), 256, 0, stream>>>(hidden, wq, Q, SEQ, DIM, DIM,
        DIM, DIM, DIM, 0, 0, 0, 1.f, 0, 0);
    gemm_nt<<<dim3(32, 32, 1), 256, 0, stream>>>(hidden, wk, K, SEQ, DIM, DIM,
        DIM, DIM, DIM, 0, 0, 0, 1.f, 0, 0);
    gemm_nt<<<dim3(32, 32, 1), 256, 0, stream>>>(hidden, wv, V, SEQ, DIM, DIM,
        DIM, DIM, DIM, 0, 0, 0, 1.f, 0, 0);

    // 2. RoPE on Q, K
    rope_qk<<<dim3(SEQ, NH / 4), 256, 0, stream>>>(Q, K, pos);

    // 3. V -> Vt[h][hd][s]  (after this, V's storage becomes O)
    transpose_v<<<dim3(SEQ / 32, HD / 32, NH), dim3(32, 32), 0, stream>>>(V, Vt);

    // 4-7 per head-group (score buffer reused across groups)
    for (int h0 = 0; h0 < NH; h0 += g) {
        int gc = min(g, NH - h0);
        // 4. per-head logits (causal tiles only): Sc[z] = (Qh @ Kh^T)/sqrt(HD)
        gemm_nt<<<dim3(32, 32, gc), 256, 0, stream>>>(
            Q + (size_t)h0 * HD, K + (size_t)h0 * HD, Sc, SEQ, SEQ, HD,
            DIM, DIM, SEQ, HD, HD, (long)SEQ * SEQ, QK_SCALE, 1, 0);
        // 5. row softmax -> scores (in place)
        softmax_rows<<<dim3(SEQ, gc), 256, 0, stream>>>(Sc);
        // 6. heavy-hitter scan: overwrites rows CACHEB.. with final probs
        h2o_scan<<<dim3(gc), 64, 0, stream>>>(Sc);
        // 7. O[h] = probs[h] @ V[h]  (A rows zero past diagonal -> truncate K)
        gemm_nt<<<dim3(HD / 64, 32, gc), 256, 0, stream>>>(
            Sc, Vt + (size_t)h0 * HD * SEQ, O + (size_t)h0 * HD, SEQ, HD, SEQ,
            SEQ, SEQ, DIM, (long)SEQ * SEQ, (long)HD * SEQ, HD, 1.f, 0, 1);
    }

    // 8. final projection: out = O @ wo^T
    gemm_nt<<<dim3(32, 32, 1), 256, 0, stream>>>(O, wo, out, SEQ, DIM, DIM,
        DIM, DIM, DIM, 0, 0, 0, 1.f, 0, 0);
}

// Round 3
// 7238.755 us; speedup vs baseline: 1.2543x; 1.2543x over previous
//
#include <hip/hip_runtime.h>
#include <math.h>

#define SEQ 2048
#define DIM 2048
#define NH 16
#define HD 128
#define CACHEB 408
#define RECENT 204
#define PEN 0.4f
#define QK_SCALE 0.08838834764831845f  // 1/sqrt(128)
#define BIGT 0x7fffffff

// ---------------- generic f32 GEMM: C = scale * A(MxK) * B(NxK)^T ----------
__global__ __launch_bounds__(256)
void gemm_nt(const float* __restrict__ A, const float* __restrict__ B,
             float* __restrict__ C, int M, int N, int K,
             int lda, int ldb, int ldc,
             long aBatch, long bBatch, long cBatch,
             float scale, int causal, int trunc_a)
{
    A += (long)blockIdx.z * aBatch;
    B += (long)blockIdx.z * bBatch;
    C += (long)blockIdx.z * cBatch;
    int m0 = blockIdx.y * 64, n0 = blockIdx.x * 64;
    if (causal && n0 > m0 + 63) return;           // tile entirely above diagonal
    int Keff = trunc_a ? min(K, m0 + 64) : K;     // A rows are zero past diag (probs)

    __shared__ float As[16][64];
    __shared__ float Bs[16][64];
    int tid = threadIdx.x;
    int tx = tid & 15, ty = tid >> 4;
    int lrow = tid >> 2;           // 0..63
    int lcol = (tid & 3) << 2;     // 0,4,8,12
    float acc[4][4] = {};

    for (int k0 = 0; k0 < Keff; k0 += 16) {
        float4 a4 = *(const float4*)(A + (size_t)(m0 + lrow) * lda + k0 + lcol);
        float4 b4 = *(const float4*)(B + (size_t)(n0 + lrow) * ldb + k0 + lcol);
        __syncthreads();
        As[lcol+0][lrow]=a4.x; As[lcol+1][lrow]=a4.y; As[lcol+2][lrow]=a4.z; As[lcol+3][lrow]=a4.w;
        Bs[lcol+0][lrow]=b4.x; Bs[lcol+1][lrow]=b4.y; Bs[lcol+2][lrow]=b4.z; Bs[lcol+3][lrow]=b4.w;
        __syncthreads();
        #pragma unroll
        for (int kk = 0; kk < 16; kk++) {
            float4 av = *(const float4*)&As[kk][ty*4];
            float4 bv = *(const float4*)&Bs[kk][tx*4];
            float a_[4] = {av.x, av.y, av.z, av.w};
            float b_[4] = {bv.x, bv.y, bv.z, bv.w};
            #pragma unroll
            for (int i = 0; i < 4; i++)
                #pragma unroll
                for (int j = 0; j < 4; j++)
                    acc[i][j] = fmaf(a_[i], b_[j], acc[i][j]);
        }
    }
    #pragma unroll
    for (int i = 0; i < 4; i++) {
        float4 o;
        o.x = acc[i][0]*scale; o.y = acc[i][1]*scale;
        o.z = acc[i][2]*scale; o.w = acc[i][3]*scale;
        *(float4*)(C + (size_t)(m0 + ty*4 + i) * ldc + n0 + tx*4) = o;
    }
}

// ---------------- RoPE in place on Q and K --------------------------------
__global__ __launch_bounds__(256)
void rope_qk(float* __restrict__ Q, float* __restrict__ K, const int* __restrict__ pos_ids)
{
    int s = blockIdx.x;
    int i = threadIdx.x & 63;
    int h = blockIdx.y * 4 + (threadIdx.x >> 6);
    double p = (double)pos_ids[s];
    double invf = exp(-((double)(2 * i) / (double)HD) * 9.210340371976184); // ln(10000)
    double ang = p * invf;
    float c = (float)cos(ang), sn = (float)sin(ang);
    size_t b = (size_t)s * DIM + (size_t)h * HD;
    float q0 = Q[b + i], q1 = Q[b + i + 64];
    Q[b + i]      = q0 * c - q1 * sn;
    Q[b + i + 64] = q1 * c + q0 * sn;
    float k0 = K[b + i], k1 = K[b + i + 64];
    K[b + i]      = k0 * c - k1 * sn;
    K[b + i + 64] = k1 * c + k0 * sn;
}

// ---------------- V -> Vt[h][hd][s] ---------------------------------------
__global__ __launch_bounds__(1024)
void transpose_v(const float* __restrict__ V, float* __restrict__ Vt)
{
    __shared__ float tile[32][33];
    int h = blockIdx.z;
    int j0 = blockIdx.x * 32, d0 = blockIdx.y * 32;
    int tx = threadIdx.x, ty = threadIdx.y;
    tile[ty][tx] = V[(size_t)(j0 + ty) * DIM + (size_t)h * HD + d0 + tx];
    __syncthreads();
    Vt[(size_t)h * HD * SEQ + (size_t)(d0 + ty) * SEQ + j0 + tx] = tile[tx][ty];
}

// ---------------- row softmax (causal) in place on Sc ---------------------
__global__ __launch_bounds__(256)
void softmax_rows(float* __restrict__ Sc)
{
    int r = blockIdx.x, h = blockIdx.y;
    float* row = Sc + ((size_t)h * SEQ + r) * SEQ;
    int n = r + 1;
    __shared__ float red[256];
    int tid = threadIdx.x;
    float mx = -INFINITY;
    for (int j = tid; j < n; j += 256) mx = fmaxf(mx, row[j]);
    red[tid] = mx; __syncthreads();
    for (int s = 128; s; s >>= 1) { if (tid < s) red[tid] = fmaxf(red[tid], red[tid + s]); __syncthreads(); }
    mx = red[0]; __syncthreads();
    float sum = 0.f;
    for (int j = tid; j < n; j += 256) { float e = expf(row[j] - mx); row[j] = e; sum += e; }
    red[tid] = sum; __syncthreads();
    for (int s = 128; s; s >>= 1) { if (tid < s) red[tid] += red[tid + s]; __syncthreads(); }
    float inv = 1.f / red[0];
    for (int j = tid; j < n; j += 256) row[j] *= inv;
    for (int j = n + tid; j < SEQ; j += 256) row[j] = 0.f;
}

// ---------------- parallel warmup: select0[h][c] = sum_t PEN^(407-t)*Sc[t][c]
__global__ __launch_bounds__(256)
void warmup_select(const float* __restrict__ Sc, float* __restrict__ sel0)
{
    int h = blockIdx.y;
    int col = blockIdx.x * 256 + threadIdx.x;
    const float* S = Sc + (size_t)h * SEQ * SEQ + col;
    float s = 0.f;
    #pragma unroll 4
    for (int t = 0; t < CACHEB; t++) s = PEN * s + S[(size_t)t * SEQ];
    sel0[h * SEQ + col] = s;
}

// ---------------- H2O greedy eviction scan (v2) ---------------------------
// One wave per head. Lane l owns cols {i*256 + l*4 + j : i in [0,8), j in [0,4)}.
// No global stores in the serial loop; outputs evict_time[col] only.
__global__ __launch_bounds__(64)
void h2o_scan2(const float* __restrict__ Sc, const float* __restrict__ sel0,
               int* __restrict__ evict)
{
    __shared__ int et[SEQ];
    int h = blockIdx.x;
    int l = threadIdx.x;
    const float* Sh = Sc + (size_t)h * SEQ * SEQ;
    const float* base = Sh + l * 4;

    #pragma unroll
    for (int s = 0; s < SEQ / 64; s++) et[s * 64 + l] = BIGT;

    float sel[32];
    const float* s0 = sel0 + h * SEQ + l * 4;
    #pragma unroll
    for (int i = 0; i < 8; i++) {
        float4 v = *(const float4*)(s0 + i * 256);
        sel[i*4+0]=v.x; sel[i*4+1]=v.y; sel[i*4+2]=v.z; sel[i*4+3]=v.w;
    }

    float4 buf0[8], buf1[8], buf2[8];
    #pragma unroll
    for (int i = 0; i < 8; i++) {
        buf0[i] = *(const float4*)(base + (size_t)(CACHEB + 0) * SEQ + i * 256);
        buf1[i] = *(const float4*)(base + (size_t)(CACHEB + 1) * SEQ + i * 256);
        buf2[i] = *(const float4*)(base + (size_t)(CACHEB + 2) * SEQ + i * 256);
    }
    unsigned mask = 0xffffffffu;   // bit k=i*4+j: col i*256+l*4+j alive

    auto step = [&](int t, float4 (&buf)[8]) {
        if (t >= SEQ - 1) return;
        float cs[32]; float part = 0.f;
        #pragma unroll
        for (int i = 0; i < 8; i++) {
            float4 b = buf[i];
            float x0 = (mask & (1u << (i*4+0))) ? b.x : 0.f;
            float x1 = (mask & (1u << (i*4+1))) ? b.y : 0.f;
            float x2 = (mask & (1u << (i*4+2))) ? b.z : 0.f;
            float x3 = (mask & (1u << (i*4+3))) ? b.w : 0.f;
            cs[i*4+0]=x0; cs[i*4+1]=x1; cs[i*4+2]=x2; cs[i*4+3]=x3;
            part += (x0 + x1) + (x2 + x3);
        }
        // refill this buffer with row t+3 (clamped; clamped rows never consumed)
        int r = t + 3; if (r > SEQ - 1) r = SEQ - 1;
        const float* nb = base + (size_t)r * SEQ;
        #pragma unroll
        for (int i = 0; i < 8; i++) buf[i] = *(const float4*)(nb + i * 256);

        #pragma unroll
        for (int off = 32; off; off >>= 1) part += __shfl_xor(part, off, 64);
        float inv = 1.f / part;

        float best = INFINITY; int bpos = BIGT;
        int lim = t - RECENT;
        int pb = l * 4;
        #pragma unroll
        for (int k = 0; k < 32; k++) {
            float c = cs[k] * inv;
            float s2 = fmaf(PEN, sel[k], c);
            sel[k] = s2;
            int p = (k >> 2) * 256 + pb + (k & 3);
            bool cand = ((mask >> k) & 1u) && (p <= lim);
            float cv = cand ? s2 : INFINITY;
            if (cv < best) { best = cv; bpos = p; }   // strict < => first index
        }
        #pragma unroll
        for (int off = 32; off; off >>= 1) {
            float ob = __shfl_xor(best, off, 64);
            int   op = __shfl_xor(bpos, off, 64);
            if (ob < best || (ob == best && op < bpos)) { best = ob; bpos = op; }
        }
        int k = ((bpos >> 8) << 2) | (bpos & 3);
        if (((bpos >> 2) & 63) == l) mask &= ~(1u << k);
        if (l == 0) et[bpos] = t;
    };

    for (int t = CACHEB; t < SEQ - 1; t += 3) {
        step(t,     buf0);
        step(t + 1, buf1);
        step(t + 2, buf2);
    }

    #pragma unroll
    for (int s = 0; s < SEQ / 64; s++)
        evict[h * SEQ + s * 64 + l] = et[s * 64 + l];
}

// ---------------- apply mask + renormalize rows >= CACHEB in place --------
// probs[r][c] = alive(r,c)*scores[r][c] / sum_alive  (exact re-softmax identity)
__global__ __launch_bounds__(256)
void mask_renorm(float* __restrict__ Sc, const int* __restrict__ evict)
{
    int r = CACHEB + blockIdx.x;
    int h = blockIdx.y;
    float* row = Sc + ((size_t)h * SEQ + r) * SEQ;
    const int* et = evict + h * SEQ;
    int tid = threadIdx.x;
    __shared__ float red[256];
    float v[8]; float sum = 0.f;
    #pragma unroll
    for (int s = 0; s < 8; s++) {
        int c = s * 256 + tid;
        float x = row[c];
        v[s] = (et[c] >= r) ? x : 0.f;
        sum += v[s];
    }
    red[tid] = sum; __syncthreads();
    for (int s = 128; s; s >>= 1) { if (tid < s) red[tid] += red[tid + s]; __syncthreads(); }
    float inv = 1.f / red[0];
    #pragma unroll
    for (int s = 0; s < 8; s++) row[s * 256 + tid] = v[s] * inv;
}

extern "C" void kernel_launch(void* const* d_in, const int* in_sizes, int n_in,
                              void* d_out, int out_size, void* d_ws, size_t ws_size,
                              hipStream_t stream)
{
    const float* hidden = (const float*)d_in[0];
    const int*   pos    = (const int*)d_in[2];
    const float* wq     = (const float*)d_in[3];
    const float* wk     = (const float*)d_in[4];
    const float* wv     = (const float*)d_in[5];
    const float* wo     = (const float*)d_in[6];
    float* out = (float*)d_out;

    float* ws = (float*)d_ws;
    const size_t SD = (size_t)SEQ * DIM;
    float* Q    = ws;            // 16 MB
    float* K    = ws + SD;       // 16 MB
    float* V    = ws + 2 * SD;   // 16 MB; reused as O after transpose_v
    float* Vt   = ws + 3 * SD;   // 16 MB
    float* O    = V;             // alias: V dead once Vt exists
    float* sel0 = ws + 4 * SD;                 // NH*SEQ floats
    int*   evct = (int*)(ws + 4 * SD + (size_t)NH * SEQ);  // NH*SEQ ints
    float* Sc   = ws + 4 * SD + 2 * (size_t)NH * SEQ;      // g * SEQ*SEQ floats

    const size_t fixedB   = (4 * SD + 2 * (size_t)NH * SEQ) * sizeof(float);
    const size_t perHeadB = (size_t)SEQ * SEQ * sizeof(float);
    int g = NH;
    while (g > 1 && fixedB + (size_t)g * perHeadB > ws_size) g >>= 1;

    // 1. projections: X @ W^T
    gemm_nt<<<dim3(32, 32, 1), 256, 0, stream>>>(hidden, wq, Q, SEQ, DIM, DIM,
        DIM, DIM, DIM, 0, 0, 0, 1.f, 0, 0);
    gemm_nt<<<dim3(32, 32, 1), 256, 0, stream>>>(hidden, wk, K, SEQ, DIM, DIM,
        DIM, DIM, DIM, 0, 0, 0, 1.f, 0, 0);
    gemm_nt<<<dim3(32, 32, 1), 256, 0, stream>>>(hidden, wv, V, SEQ, DIM, DIM,
        DIM, DIM, DIM, 0, 0, 0, 1.f, 0, 0);

    // 2. RoPE on Q, K
    rope_qk<<<dim3(SEQ, NH / 4), 256, 0, stream>>>(Q, K, pos);

    // 3. V -> Vt[h][hd][s]  (after this, V's storage becomes O)
    transpose_v<<<dim3(SEQ / 32, HD / 32, NH), dim3(32, 32), 0, stream>>>(V, Vt);

    // 4-8 per head-group (score buffer reused across groups)
    for (int h0 = 0; h0 < NH; h0 += g) {
        int gc = min(g, NH - h0);
        gemm_nt<<<dim3(32, 32, gc), 256, 0, stream>>>(
            Q + (size_t)h0 * HD, K + (size_t)h0 * HD, Sc, SEQ, SEQ, HD,
            DIM, DIM, SEQ, HD, HD, (long)SEQ * SEQ, QK_SCALE, 1, 0);
        softmax_rows<<<dim3(SEQ, gc), 256, 0, stream>>>(Sc);
        warmup_select<<<dim3(SEQ / 256, gc), 256, 0, stream>>>(Sc, sel0);
        h2o_scan2<<<dim3(gc), 64, 0, stream>>>(Sc, sel0, evct);
        mask_renorm<<<dim3(SEQ - CACHEB, gc), 256, 0, stream>>>(Sc, evct);
        gemm_nt<<<dim3(HD / 64, 32, gc), 256, 0, stream>>>(
            Sc, Vt + (size_t)h0 * HD * SEQ, O + (size_t)h0 * HD, SEQ, HD, SEQ,
            SEQ, SEQ, DIM, (long)SEQ * SEQ, (long)HD * SEQ, HD, 1.f, 0, 1);
    }

    // 9. final projection: out = O @ wo^T
    gemm_nt<<<dim3(32, 32, 1), 256, 0, stream>>>(O, wo, out, SEQ, DIM, DIM,
        DIM, DIM, DIM, 0, 0, 0, 1.f, 0, 0);
}

// Round 4
// 6630.148 us; speedup vs baseline: 1.3694x; 1.0918x over previous
//
#include <hip/hip_runtime.h>
#include <math.h>

#define SEQ 2048
#define DIM 2048
#define NH 16
#define HD 128
#define CACHEB 408
#define RECENT 204
#define PEN 0.4f
#define QK_SCALE 0.08838834764831845f  // 1/sqrt(128)
#define BIGT 0x7fffffff

// ---------------- generic f32 GEMM: C = scale * A(MxK) * B(NxK)^T ----------
__global__ __launch_bounds__(256)
void gemm_nt(const float* __restrict__ A, const float* __restrict__ B,
             float* __restrict__ C, int M, int N, int K,
             int lda, int ldb, int ldc,
             long aBatch, long bBatch, long cBatch,
             float scale, int causal, int trunc_a)
{
    A += (long)blockIdx.z * aBatch;
    B += (long)blockIdx.z * bBatch;
    C += (long)blockIdx.z * cBatch;
    int m0 = blockIdx.y * 64, n0 = blockIdx.x * 64;
    if (causal && n0 > m0 + 63) return;           // tile entirely above diagonal
    int Keff = trunc_a ? min(K, m0 + 64) : K;     // A rows are zero past diag (probs)

    __shared__ float As[16][64];
    __shared__ float Bs[16][64];
    int tid = threadIdx.x;
    int tx = tid & 15, ty = tid >> 4;
    int lrow = tid >> 2;           // 0..63
    int lcol = (tid & 3) << 2;     // 0,4,8,12
    float acc[4][4] = {};

    for (int k0 = 0; k0 < Keff; k0 += 16) {
        float4 a4 = *(const float4*)(A + (size_t)(m0 + lrow) * lda + k0 + lcol);
        float4 b4 = *(const float4*)(B + (size_t)(n0 + lrow) * ldb + k0 + lcol);
        __syncthreads();
        As[lcol+0][lrow]=a4.x; As[lcol+1][lrow]=a4.y; As[lcol+2][lrow]=a4.z; As[lcol+3][lrow]=a4.w;
        Bs[lcol+0][lrow]=b4.x; Bs[lcol+1][lrow]=b4.y; Bs[lcol+2][lrow]=b4.z; Bs[lcol+3][lrow]=b4.w;
        __syncthreads();
        #pragma unroll
        for (int kk = 0; kk < 16; kk++) {
            float4 av = *(const float4*)&As[kk][ty*4];
            float4 bv = *(const float4*)&Bs[kk][tx*4];
            float a_[4] = {av.x, av.y, av.z, av.w};
            float b_[4] = {bv.x, bv.y, bv.z, bv.w};
            #pragma unroll
            for (int i = 0; i < 4; i++)
                #pragma unroll
                for (int j = 0; j < 4; j++)
                    acc[i][j] = fmaf(a_[i], b_[j], acc[i][j]);
        }
    }
    #pragma unroll
    for (int i = 0; i < 4; i++) {
        float4 o;
        o.x = acc[i][0]*scale; o.y = acc[i][1]*scale;
        o.z = acc[i][2]*scale; o.w = acc[i][3]*scale;
        *(float4*)(C + (size_t)(m0 + ty*4 + i) * ldc + n0 + tx*4) = o;
    }
}

// ---------------- RoPE in place on Q and K --------------------------------
__global__ __launch_bounds__(256)
void rope_qk(float* __restrict__ Q, float* __restrict__ K, const int* __restrict__ pos_ids)
{
    int s = blockIdx.x;
    int i = threadIdx.x & 63;
    int h = blockIdx.y * 4 + (threadIdx.x >> 6);
    double p = (double)pos_ids[s];
    double invf = exp(-((double)(2 * i) / (double)HD) * 9.210340371976184); // ln(10000)
    double ang = p * invf;
    float c = (float)cos(ang), sn = (float)sin(ang);
    size_t b = (size_t)s * DIM + (size_t)h * HD;
    float q0 = Q[b + i], q1 = Q[b + i + 64];
    Q[b + i]      = q0 * c - q1 * sn;
    Q[b + i + 64] = q1 * c + q0 * sn;
    float k0 = K[b + i], k1 = K[b + i + 64];
    K[b + i]      = k0 * c - k1 * sn;
    K[b + i + 64] = k1 * c + k0 * sn;
}

// ---------------- V -> Vt[h][hd][s] ---------------------------------------
__global__ __launch_bounds__(1024)
void transpose_v(const float* __restrict__ V, float* __restrict__ Vt)
{
    __shared__ float tile[32][33];
    int h = blockIdx.z;
    int j0 = blockIdx.x * 32, d0 = blockIdx.y * 32;
    int tx = threadIdx.x, ty = threadIdx.y;
    tile[ty][tx] = V[(size_t)(j0 + ty) * DIM + (size_t)h * HD + d0 + tx];
    __syncthreads();
    Vt[(size_t)h * HD * SEQ + (size_t)(d0 + ty) * SEQ + j0 + tx] = tile[tx][ty];
}

// ---------------- row softmax (causal) in place on Sc ---------------------
__global__ __launch_bounds__(256)
void softmax_rows(float* __restrict__ Sc)
{
    int r = blockIdx.x, h = blockIdx.y;
    float* row = Sc + ((size_t)h * SEQ + r) * SEQ;
    int n = r + 1;
    __shared__ float red[256];
    int tid = threadIdx.x;
    float mx = -INFINITY;
    for (int j = tid; j < n; j += 256) mx = fmaxf(mx, row[j]);
    red[tid] = mx; __syncthreads();
    for (int s = 128; s; s >>= 1) { if (tid < s) red[tid] = fmaxf(red[tid], red[tid + s]); __syncthreads(); }
    mx = red[0]; __syncthreads();
    float sum = 0.f;
    for (int j = tid; j < n; j += 256) { float e = expf(row[j] - mx); row[j] = e; sum += e; }
    red[tid] = sum; __syncthreads();
    for (int s = 128; s; s >>= 1) { if (tid < s) red[tid] += red[tid + s]; __syncthreads(); }
    float inv = 1.f / red[0];
    for (int j = tid; j < n; j += 256) row[j] *= inv;
    for (int j = n + tid; j < SEQ; j += 256) row[j] = 0.f;
}

// ---------------- parallel warmup: select0[h][c] = sum_t PEN^(407-t)*Sc[t][c]
__global__ __launch_bounds__(256)
void warmup_select(const float* __restrict__ Sc, float* __restrict__ sel0)
{
    int h = blockIdx.y;
    int col = blockIdx.x * 256 + threadIdx.x;
    const float* S = Sc + (size_t)h * SEQ * SEQ + col;
    float s = 0.f;
    #pragma unroll 4
    for (int t = 0; t < CACHEB; t++) s = PEN * s + S[(size_t)t * SEQ];
    sel0[h * SEQ + col] = s;
}

// ---------------- H2O greedy eviction scan (v3) ---------------------------
// One wave per head. Lane l owns cols {i*256 + l*4 + j : i in [0,8), j in [0,4)}.
// No global stores in the serial loop; outputs evict_time[col] only.
// launch_bounds(64,1): full 512-VGPR budget -> no scratch spills.
__global__ __launch_bounds__(64, 1)
void h2o_scan2(const float* __restrict__ Sc, const float* __restrict__ sel0,
               int* __restrict__ evict)
{
    __shared__ int et[SEQ];
    int h = blockIdx.x;
    int l = threadIdx.x;
    const float* Sh = Sc + (size_t)h * SEQ * SEQ;
    const float* base = Sh + l * 4;

    #pragma unroll
    for (int s = 0; s < SEQ / 64; s++) et[s * 64 + l] = BIGT;

    float sel[32];
    const float* s0 = sel0 + h * SEQ + l * 4;
    #pragma unroll
    for (int i = 0; i < 8; i++) {
        float4 v = *(const float4*)(s0 + i * 256);
        sel[i*4+0]=v.x; sel[i*4+1]=v.y; sel[i*4+2]=v.z; sel[i*4+3]=v.w;
    }

    float4 buf0[8], buf1[8], buf2[8];
    #pragma unroll
    for (int i = 0; i < 8; i++) {
        buf0[i] = *(const float4*)(base + (size_t)(CACHEB + 0) * SEQ + i * 256);
        buf1[i] = *(const float4*)(base + (size_t)(CACHEB + 1) * SEQ + i * 256);
        buf2[i] = *(const float4*)(base + (size_t)(CACHEB + 2) * SEQ + i * 256);
    }
    unsigned mask = 0xffffffffu;   // bit k=i*4+j: col i*256+l*4+j alive

    auto step = [&](int t, float4 (&buf)[8]) {
        if (t >= SEQ - 1) return;
        // ---- pass 1: masked partial sum (4 independent chains) ----
        float p0 = 0.f, p1 = 0.f, p2 = 0.f, p3 = 0.f;
        #pragma unroll
        for (int i = 0; i < 8; i++) {
            float4 b = buf[i];
            p0 += (mask & (1u << (i*4+0))) ? b.x : 0.f;
            p1 += (mask & (1u << (i*4+1))) ? b.y : 0.f;
            p2 += (mask & (1u << (i*4+2))) ? b.z : 0.f;
            p3 += (mask & (1u << (i*4+3))) ? b.w : 0.f;
        }
        float part = (p0 + p1) + (p2 + p3);
        // pre-scale sel while the butterfly is in flight (independent of inv)
        #pragma unroll
        for (int k = 0; k < 32; k++) sel[k] *= PEN;
        #pragma unroll
        for (int off = 32; off; off >>= 1) part += __shfl_xor(part, off, 64);
        float inv = 1.f / part;

        // ---- pass 2: sel update + u64-key argmin ----
        // key = (bits(sel)<<32)|pos ; sel>=0 so IEEE bits are order-preserving.
        // u64 min == (min value, then min pos) == numpy first-index argmin.
        int lim = t - RECENT;
        int pb = l * 4;
        unsigned long long gbest[4];
        #pragma unroll
        for (int gI = 0; gI < 4; gI++) {
            unsigned long long kk[8];
            #pragma unroll
            for (int j = 0; j < 8; j++) {
                int k = gI * 8 + j;
                int i = k >> 2, jj = k & 3;
                float4 b = buf[i];
                float x = (jj == 0) ? b.x : (jj == 1) ? b.y : (jj == 2) ? b.z : b.w;
                float mv = (mask & (1u << k)) ? x : 0.f;
                float s2 = fmaf(mv, inv, sel[k]);
                sel[k] = s2;
                int p = (i << 8) + pb + jj;
                bool cand = ((mask >> k) & 1u) && (p <= lim);
                kk[j] = cand ? (((unsigned long long)__float_as_uint(s2) << 32) | (unsigned)p)
                             : ~0ull;
            }
            #pragma unroll
            for (int w = 4; w; w >>= 1)
                #pragma unroll
                for (int j = 0; j < w; j++)
                    kk[j] = kk[j + w] < kk[j] ? kk[j + w] : kk[j];
            gbest[gI] = kk[0];
        }
        unsigned long long b01 = gbest[1] < gbest[0] ? gbest[1] : gbest[0];
        unsigned long long b23 = gbest[3] < gbest[2] ? gbest[3] : gbest[2];
        unsigned long long bkey = b23 < b01 ? b23 : b01;
        #pragma unroll
        for (int off = 32; off; off >>= 1) {
            unsigned long long o = __shfl_xor(bkey, off, 64);
            bkey = o < bkey ? o : bkey;
        }
        int bpos = (int)(unsigned)bkey;
        int ke = (((bpos >> 8) << 2) | (bpos & 3));
        if (((bpos >> 2) & 63) == l) mask &= ~(1u << ke);
        if (l == 0) et[bpos] = t;

        // ---- refill this buffer with row t+3 (consumed ~3 steps later) ----
        int r = t + 3; if (r > SEQ - 1) r = SEQ - 1;
        const float* nb = base + (size_t)r * SEQ;
        #pragma unroll
        for (int i = 0; i < 8; i++) buf[i] = *(const float4*)(nb + i * 256);
    };

    for (int t = CACHEB; t < SEQ - 1; t += 3) {
        step(t,     buf0);
        step(t + 1, buf1);
        step(t + 2, buf2);
    }

    #pragma unroll
    for (int s = 0; s < SEQ / 64; s++)
        evict[h * SEQ + s * 64 + l] = et[s * 64 + l];
}

// ---------------- apply mask + renormalize rows >= CACHEB in place --------
__global__ __launch_bounds__(256)
void mask_renorm(float* __restrict__ Sc, const int* __restrict__ evict)
{
    int r = CACHEB + blockIdx.x;
    int h = blockIdx.y;
    float* row = Sc + ((size_t)h * SEQ + r) * SEQ;
    const int* et = evict + h * SEQ;
    int tid = threadIdx.x;
    __shared__ float red[256];
    float v[8]; float sum = 0.f;
    #pragma unroll
    for (int s = 0; s < 8; s++) {
        int c = s * 256 + tid;
        float x = row[c];
        v[s] = (et[c] >= r) ? x : 0.f;
        sum += v[s];
    }
    red[tid] = sum; __syncthreads();
    for (int s = 128; s; s >>= 1) { if (tid < s) red[tid] += red[tid + s]; __syncthreads(); }
    float inv = 1.f / red[0];
    #pragma unroll
    for (int s = 0; s < 8; s++) row[s * 256 + tid] = v[s] * inv;
}

extern "C" void kernel_launch(void* const* d_in, const int* in_sizes, int n_in,
                              void* d_out, int out_size, void* d_ws, size_t ws_size,
                              hipStream_t stream)
{
    const float* hidden = (const float*)d_in[0];
    const int*   pos    = (const int*)d_in[2];
    const float* wq     = (const float*)d_in[3];
    const float* wk     = (const float*)d_in[4];
    const float* wv     = (const float*)d_in[5];
    const float* wo     = (const float*)d_in[6];
    float* out = (float*)d_out;

    float* ws = (float*)d_ws;
    const size_t SD = (size_t)SEQ * DIM;
    float* Q    = ws;            // 16 MB
    float* K    = ws + SD;       // 16 MB
    float* V    = ws + 2 * SD;   // 16 MB; reused as O after transpose_v
    float* Vt   = ws + 3 * SD;   // 16 MB
    float* O    = V;             // alias: V dead once Vt exists
    float* sel0 = ws + 4 * SD;                 // NH*SEQ floats
    int*   evct = (int*)(ws + 4 * SD + (size_t)NH * SEQ);  // NH*SEQ ints
    float* Sc   = ws + 4 * SD + 2 * (size_t)NH * SEQ;      // g * SEQ*SEQ floats

    const size_t fixedB   = (4 * SD + 2 * (size_t)NH * SEQ) * sizeof(float);
    const size_t perHeadB = (size_t)SEQ * SEQ * sizeof(float);
    int g = NH;
    while (g > 1 && fixedB + (size_t)g * perHeadB > ws_size) g >>= 1;

    // 1. projections: X @ W^T
    gemm_nt<<<dim3(32, 32, 1), 256, 0, stream>>>(hidden, wq, Q, SEQ, DIM, DIM,
        DIM, DIM, DIM, 0, 0, 0, 1.f, 0, 0);
    gemm_nt<<<dim3(32, 32, 1), 256, 0, stream>>>(hidden, wk, K, SEQ, DIM, DIM,
        DIM, DIM, DIM, 0, 0, 0, 1.f, 0, 0);
    gemm_nt<<<dim3(32, 32, 1), 256, 0, stream>>>(hidden, wv, V, SEQ, DIM, DIM,
        DIM, DIM, DIM, 0, 0, 0, 1.f, 0, 0);

    // 2. RoPE on Q, K
    rope_qk<<<dim3(SEQ, NH / 4), 256, 0, stream>>>(Q, K, pos);

    // 3. V -> Vt[h][hd][s]  (after this, V's storage becomes O)
    transpose_v<<<dim3(SEQ / 32, HD / 32, NH), dim3(32, 32), 0, stream>>>(V, Vt);

    // 4-8 per head-group (score buffer reused across groups)
    for (int h0 = 0; h0 < NH; h0 += g) {
        int gc = min(g, NH - h0);
        gemm_nt<<<dim3(32, 32, gc), 256, 0, stream>>>(
            Q + (size_t)h0 * HD, K + (size_t)h0 * HD, Sc, SEQ, SEQ, HD,
            DIM, DIM, SEQ, HD, HD, (long)SEQ * SEQ, QK_SCALE, 1, 0);
        softmax_rows<<<dim3(SEQ, gc), 256, 0, stream>>>(Sc);
        warmup_select<<<dim3(SEQ / 256, gc), 256, 0, stream>>>(Sc, sel0);
        h2o_scan2<<<dim3(gc), 64, 0, stream>>>(Sc, sel0, evct);
        mask_renorm<<<dim3(SEQ - CACHEB, gc), 256, 0, stream>>>(Sc, evct);
        gemm_nt<<<dim3(HD / 64, 32, gc), 256, 0, stream>>>(
            Sc, Vt + (size_t)h0 * HD * SEQ, O + (size_t)h0 * HD, SEQ, HD, SEQ,
            SEQ, SEQ, DIM, (long)SEQ * SEQ, (long)HD * SEQ, HD, 1.f, 0, 1);
    }

    // 9. final projection: out = O @ wo^T
    gemm_nt<<<dim3(32, 32, 1), 256, 0, stream>>>(O, wo, out, SEQ, DIM, DIM,
        DIM, DIM, DIM, 0, 0, 0, 1.f, 0, 0);
}

// Round 5
// 5992.591 us; speedup vs baseline: 1.5151x; 1.1064x over previous
//
#include <hip/hip_runtime.h>
#include <math.h>

#define SEQ 2048
#define DIM 2048
#define NH 16
#define HD 128
#define CACHEB 408
#define RECENT 204
#define PEN 0.4f
#define QK_SCALE 0.08838834764831845f  // 1/sqrt(128)
#define BIGT 0x7fffffff

// ---------------- generic f32 GEMM: C = scale * A(MxK) * B(NxK)^T ----------
__global__ __launch_bounds__(256)
void gemm_nt(const float* __restrict__ A, const float* __restrict__ B,
             float* __restrict__ C, int M, int N, int K,
             int lda, int ldb, int ldc,
             long aBatch, long bBatch, long cBatch,
             float scale, int causal, int trunc_a)
{
    A += (long)blockIdx.z * aBatch;
    B += (long)blockIdx.z * bBatch;
    C += (long)blockIdx.z * cBatch;
    int m0 = blockIdx.y * 64, n0 = blockIdx.x * 64;
    if (causal && n0 > m0 + 63) return;           // tile entirely above diagonal
    int Keff = trunc_a ? min(K, m0 + 64) : K;     // A rows are zero past diag (probs)

    __shared__ float As[16][64];
    __shared__ float Bs[16][64];
    int tid = threadIdx.x;
    int tx = tid & 15, ty = tid >> 4;
    int lrow = tid >> 2;           // 0..63
    int lcol = (tid & 3) << 2;     // 0,4,8,12
    float acc[4][4] = {};

    for (int k0 = 0; k0 < Keff; k0 += 16) {
        float4 a4 = *(const float4*)(A + (size_t)(m0 + lrow) * lda + k0 + lcol);
        float4 b4 = *(const float4*)(B + (size_t)(n0 + lrow) * ldb + k0 + lcol);
        __syncthreads();
        As[lcol+0][lrow]=a4.x; As[lcol+1][lrow]=a4.y; As[lcol+2][lrow]=a4.z; As[lcol+3][lrow]=a4.w;
        Bs[lcol+0][lrow]=b4.x; Bs[lcol+1][lrow]=b4.y; Bs[lcol+2][lrow]=b4.z; Bs[lcol+3][lrow]=b4.w;
        __syncthreads();
        #pragma unroll
        for (int kk = 0; kk < 16; kk++) {
            float4 av = *(const float4*)&As[kk][ty*4];
            float4 bv = *(const float4*)&Bs[kk][tx*4];
            float a_[4] = {av.x, av.y, av.z, av.w};
            float b_[4] = {bv.x, bv.y, bv.z, bv.w};
            #pragma unroll
            for (int i = 0; i < 4; i++)
                #pragma unroll
                for (int j = 0; j < 4; j++)
                    acc[i][j] = fmaf(a_[i], b_[j], acc[i][j]);
        }
    }
    #pragma unroll
    for (int i = 0; i < 4; i++) {
        float4 o;
        o.x = acc[i][0]*scale; o.y = acc[i][1]*scale;
        o.z = acc[i][2]*scale; o.w = acc[i][3]*scale;
        *(float4*)(C + (size_t)(m0 + ty*4 + i) * ldc + n0 + tx*4) = o;
    }
}

// ---------------- RoPE in place on Q and K --------------------------------
__global__ __launch_bounds__(256)
void rope_qk(float* __restrict__ Q, float* __restrict__ K, const int* __restrict__ pos_ids)
{
    int s = blockIdx.x;
    int i = threadIdx.x & 63;
    int h = blockIdx.y * 4 + (threadIdx.x >> 6);
    double p = (double)pos_ids[s];
    double invf = exp(-((double)(2 * i) / (double)HD) * 9.210340371976184); // ln(10000)
    double ang = p * invf;
    float c = (float)cos(ang), sn = (float)sin(ang);
    size_t b = (size_t)s * DIM + (size_t)h * HD;
    float q0 = Q[b + i], q1 = Q[b + i + 64];
    Q[b + i]      = q0 * c - q1 * sn;
    Q[b + i + 64] = q1 * c + q0 * sn;
    float k0 = K[b + i], k1 = K[b + i + 64];
    K[b + i]      = k0 * c - k1 * sn;
    K[b + i + 64] = k1 * c + k0 * sn;
}

// ---------------- V -> Vt[h][hd][s] ---------------------------------------
__global__ __launch_bounds__(1024)
void transpose_v(const float* __restrict__ V, float* __restrict__ Vt)
{
    __shared__ float tile[32][33];
    int h = blockIdx.z;
    int j0 = blockIdx.x * 32, d0 = blockIdx.y * 32;
    int tx = threadIdx.x, ty = threadIdx.y;
    tile[ty][tx] = V[(size_t)(j0 + ty) * DIM + (size_t)h * HD + d0 + tx];
    __syncthreads();
    Vt[(size_t)h * HD * SEQ + (size_t)(d0 + ty) * SEQ + j0 + tx] = tile[tx][ty];
}

// ---------------- row softmax (causal) in place on Sc ---------------------
__global__ __launch_bounds__(256)
void softmax_rows(float* __restrict__ Sc)
{
    int r = blockIdx.x, h = blockIdx.y;
    float* row = Sc + ((size_t)h * SEQ + r) * SEQ;
    int n = r + 1;
    __shared__ float red[256];
    int tid = threadIdx.x;
    float mx = -INFINITY;
    for (int j = tid; j < n; j += 256) mx = fmaxf(mx, row[j]);
    red[tid] = mx; __syncthreads();
    for (int s = 128; s; s >>= 1) { if (tid < s) red[tid] = fmaxf(red[tid], red[tid + s]); __syncthreads(); }
    mx = red[0]; __syncthreads();
    float sum = 0.f;
    for (int j = tid; j < n; j += 256) { float e = expf(row[j] - mx); row[j] = e; sum += e; }
    red[tid] = sum; __syncthreads();
    for (int s = 128; s; s >>= 1) { if (tid < s) red[tid] += red[tid + s]; __syncthreads(); }
    float inv = 1.f / red[0];
    for (int j = tid; j < n; j += 256) row[j] *= inv;
    for (int j = n + tid; j < SEQ; j += 256) row[j] = 0.f;
}

// ---------------- parallel warmup: select0[h][c] = sum_t PEN^(407-t)*Sc[t][c]
__global__ __launch_bounds__(256)
void warmup_select(const float* __restrict__ Sc, float* __restrict__ sel0)
{
    int h = blockIdx.y;
    int col = blockIdx.x * 256 + threadIdx.x;
    const float* S = Sc + (size_t)h * SEQ * SEQ + col;
    float s = 0.f;
    #pragma unroll 4
    for (int t = 0; t < CACHEB; t++) s = PEN * s + S[(size_t)t * SEQ];
    sel0[h * SEQ + col] = s;
}

// ---------------- DPP cross-lane helpers (VALU-speed, no LDS) -------------
// row_shr:N = 0x110+N; row_bcast15 = 0x142; row_bcast31 = 0x143.
#define DPP_SUMSTEP(x, ctrl) \
    x += __int_as_float(__builtin_amdgcn_update_dpp(0, __float_as_int(x), ctrl, 0xF, 0xF, true))
#define DPP_SUMBC(x, ctrl) \
    x += __int_as_float(__builtin_amdgcn_update_dpp(0, __float_as_int(x), ctrl, 0xF, 0xF, false))
#define DPP_MINF(x, ctrl) \
    x = fminf(x, __int_as_float(__builtin_amdgcn_update_dpp(__float_as_int(x), __float_as_int(x), ctrl, 0xF, 0xF, false)))
#define DPP_MINU(x, ctrl) \
    { unsigned t_ = (unsigned)__builtin_amdgcn_update_dpp((int)(x), (int)(x), ctrl, 0xF, 0xF, false); x = t_ < x ? t_ : x; }

__device__ __forceinline__ float wave_sum64(float x) {
    DPP_SUMSTEP(x, 0x111); DPP_SUMSTEP(x, 0x112);
    DPP_SUMSTEP(x, 0x114); DPP_SUMSTEP(x, 0x118);
    DPP_SUMBC(x, 0x142);   DPP_SUMBC(x, 0x143);
    return __int_as_float(__builtin_amdgcn_readlane(__float_as_int(x), 63));
}
__device__ __forceinline__ float wave_min64f(float x) {
    DPP_MINF(x, 0x111); DPP_MINF(x, 0x112);
    DPP_MINF(x, 0x114); DPP_MINF(x, 0x118);
    DPP_MINF(x, 0x142); DPP_MINF(x, 0x143);
    return __int_as_float(__builtin_amdgcn_readlane(__float_as_int(x), 63));
}
__device__ __forceinline__ unsigned wave_min64u(unsigned x) {
    DPP_MINU(x, 0x111); DPP_MINU(x, 0x112);
    DPP_MINU(x, 0x114); DPP_MINU(x, 0x118);
    DPP_MINU(x, 0x142); DPP_MINU(x, 0x143);
    return (unsigned)__builtin_amdgcn_readlane((int)x, 63);
}

// ---------------- H2O greedy eviction scan (v4, DPP) ----------------------
// One wave per head. Lane l owns cols {i*256 + l*4 + j : i in [0,8), j in [0,4)}.
// No global stores in the serial loop; outputs evict_time[col] only.
__global__ __launch_bounds__(64, 1)
void h2o_scan2(const float* __restrict__ Sc, const float* __restrict__ sel0,
               int* __restrict__ evict)
{
    __shared__ int et[SEQ];
    int h = blockIdx.x;
    int l = threadIdx.x;
    const float* Sh = Sc + (size_t)h * SEQ * SEQ;
    const float* base = Sh + l * 4;

    #pragma unroll
    for (int s = 0; s < SEQ / 64; s++) et[s * 64 + l] = BIGT;

    float sel[32];
    const float* s0 = sel0 + h * SEQ + l * 4;
    #pragma unroll
    for (int i = 0; i < 8; i++) {
        float4 v = *(const float4*)(s0 + i * 256);
        sel[i*4+0]=v.x; sel[i*4+1]=v.y; sel[i*4+2]=v.z; sel[i*4+3]=v.w;
    }

    float4 buf0[8], buf1[8], buf2[8];
    #pragma unroll
    for (int i = 0; i < 8; i++) {
        buf0[i] = *(const float4*)(base + (size_t)(CACHEB + 0) * SEQ + i * 256);
        buf1[i] = *(const float4*)(base + (size_t)(CACHEB + 1) * SEQ + i * 256);
        buf2[i] = *(const float4*)(base + (size_t)(CACHEB + 2) * SEQ + i * 256);
    }
    unsigned mask = 0xffffffffu;     // bit k=i*4+j: col i*256+l*4+j alive
    unsigned candBits = 0;           // bit k: col <= t-RECENT (incremental)
    #pragma unroll
    for (int k = 0; k < 32; k++) {
        int p = ((k >> 2) << 8) + l * 4 + (k & 3);
        if (p <= CACHEB - RECENT) candBits |= 1u << k;
    }

    auto step = [&](int t, float4 (&buf)[8]) {
        if (t >= SEQ - 1) return;
        // ---- masked sum over alive cols (4 independent chains) ----
        float p0 = 0.f, p1 = 0.f, p2 = 0.f, p3 = 0.f;
        #pragma unroll
        for (int i = 0; i < 8; i++) {
            float4 b = buf[i];
            p0 += (mask & (1u << (i*4+0))) ? b.x : 0.f;
            p1 += (mask & (1u << (i*4+1))) ? b.y : 0.f;
            p2 += (mask & (1u << (i*4+2))) ? b.z : 0.f;
            p3 += (mask & (1u << (i*4+3))) ? b.w : 0.f;
        }
        float part = wave_sum64((p0 + p1) + (p2 + p3));
        float inv = 1.f / part;

        // ---- sel update + candidate-masked value ----
        unsigned cm = mask & candBits;
        float cv[32];
        #pragma unroll
        for (int k = 0; k < 32; k++) {
            int i = k >> 2, jj = k & 3;
            float4 b = buf[i];
            float x = (jj == 0) ? b.x : (jj == 1) ? b.y : (jj == 2) ? b.z : b.w;
            float mv = (mask & (1u << k)) ? x : 0.f;
            float s2 = fmaf(PEN, sel[k], mv * inv);
            sel[k] = s2;
            cv[k] = ((cm >> k) & 1u) ? s2 : INFINITY;
        }
        // ---- local min value (tree), then DPP min across lanes ----
        float m16[16];
        #pragma unroll
        for (int k = 0; k < 16; k++) m16[k] = fminf(cv[k], cv[k + 16]);
        float m8[8];
        #pragma unroll
        for (int k = 0; k < 8; k++) m8[k] = fminf(m16[k], m16[k + 8]);
        float m4[4];
        #pragma unroll
        for (int k = 0; k < 4; k++) m4[k] = fminf(m8[k], m8[k + 4]);
        float lmin = fminf(fminf(m4[0], m4[1]), fminf(m4[2], m4[3]));
        float gm = wave_min64f(lmin);

        // ---- first matching column: bitmask + ffs, then DPP min pos ----
        unsigned mb = 0;
        #pragma unroll
        for (int k = 0; k < 32; k++) mb |= (cv[k] == gm) ? (1u << k) : 0u;
        int mk = __ffs(mb) - 1;       // -1 if no match on this lane
        unsigned lpos = mb ? (unsigned)(((mk >> 2) << 8) + l * 4 + (mk & 3))
                           : 0xffffffffu;
        unsigned bpos = wave_min64u(lpos);

        // ---- evict ----
        int ke = (((bpos >> 8) << 2) | (bpos & 3));
        if ((((int)bpos >> 2) & 63) == l) mask &= ~(1u << ke);
        if (l == 0) et[bpos] = t;

        // ---- candidate set grows by one col for step t+1 ----
        int newc = t + 1 - RECENT;
        if (((newc >> 2) & 63) == l) candBits |= 1u << (((newc >> 8) << 2) | (newc & 3));

        // ---- refill this buffer with row t+3 (consumed 3 steps later) ----
        int r = t + 3; if (r > SEQ - 1) r = SEQ - 1;
        const float* nb = base + (size_t)r * SEQ;
        #pragma unroll
        for (int i = 0; i < 8; i++) buf[i] = *(const float4*)(nb + i * 256);
    };

    for (int t = CACHEB; t < SEQ - 1; t += 3) {
        step(t,     buf0);
        step(t + 1, buf1);
        step(t + 2, buf2);
    }

    #pragma unroll
    for (int s = 0; s < SEQ / 64; s++)
        evict[h * SEQ + s * 64 + l] = et[s * 64 + l];
}

// ---------------- apply mask + renormalize rows >= CACHEB in place --------
__global__ __launch_bounds__(256)
void mask_renorm(float* __restrict__ Sc, const int* __restrict__ evict)
{
    int r = CACHEB + blockIdx.x;
    int h = blockIdx.y;
    float* row = Sc + ((size_t)h * SEQ + r) * SEQ;
    const int* et = evict + h * SEQ;
    int tid = threadIdx.x;
    __shared__ float red[256];
    float v[8]; float sum = 0.f;
    #pragma unroll
    for (int s = 0; s < 8; s++) {
        int c = s * 256 + tid;
        float x = row[c];
        v[s] = (et[c] >= r) ? x : 0.f;
        sum += v[s];
    }
    red[tid] = sum; __syncthreads();
    for (int s = 128; s; s >>= 1) { if (tid < s) red[tid] += red[tid + s]; __syncthreads(); }
    float inv = 1.f / red[0];
    #pragma unroll
    for (int s = 0; s < 8; s++) row[s * 256 + tid] = v[s] * inv;
}

extern "C" void kernel_launch(void* const* d_in, const int* in_sizes, int n_in,
                              void* d_out, int out_size, void* d_ws, size_t ws_size,
                              hipStream_t stream)
{
    const float* hidden = (const float*)d_in[0];
    const int*   pos    = (const int*)d_in[2];
    const float* wq     = (const float*)d_in[3];
    const float* wk     = (const float*)d_in[4];
    const float* wv     = (const float*)d_in[5];
    const float* wo     = (const float*)d_in[6];
    float* out = (float*)d_out;

    float* ws = (float*)d_ws;
    const size_t SD = (size_t)SEQ * DIM;
    float* Q    = ws;            // 16 MB
    float* K    = ws + SD;       // 16 MB
    float* V    = ws + 2 * SD;   // 16 MB; reused as O after transpose_v
    float* Vt   = ws + 3 * SD;   // 16 MB
    float* O    = V;             // alias: V dead once Vt exists
    float* sel0 = ws + 4 * SD;                 // NH*SEQ floats
    int*   evct = (int*)(ws + 4 * SD + (size_t)NH * SEQ);  // NH*SEQ ints
    float* Sc   = ws + 4 * SD + 2 * (size_t)NH * SEQ;      // g * SEQ*SEQ floats

    const size_t fixedB   = (4 * SD + 2 * (size_t)NH * SEQ) * sizeof(float);
    const size_t perHeadB = (size_t)SEQ * SEQ * sizeof(float);
    int g = NH;
    while (g > 1 && fixedB + (size_t)g * perHeadB > ws_size) g >>= 1;

    // 1. projections: X @ W^T
    gemm_nt<<<dim3(32, 32, 1), 256, 0, stream>>>(hidden, wq, Q, SEQ, DIM, DIM,
        DIM, DIM, DIM, 0, 0, 0, 1.f, 0, 0);
    gemm_nt<<<dim3(32, 32, 1), 256, 0, stream>>>(hidden, wk, K, SEQ, DIM, DIM,
        DIM, DIM, DIM, 0, 0, 0, 1.f, 0, 0);
    gemm_nt<<<dim3(32, 32, 1), 256, 0, stream>>>(hidden, wv, V, SEQ, DIM, DIM,
        DIM, DIM, DIM, 0, 0, 0, 1.f, 0, 0);

    // 2. RoPE on Q, K
    rope_qk<<<dim3(SEQ, NH / 4), 256, 0, stream>>>(Q, K, pos);

    // 3. V -> Vt[h][hd][s]  (after this, V's storage becomes O)
    transpose_v<<<dim3(SEQ / 32, HD / 32, NH), dim3(32, 32), 0, stream>>>(V, Vt);

    // 4-8 per head-group (score buffer reused across groups)
    for (int h0 = 0; h0 < NH; h0 += g) {
        int gc = min(g, NH - h0);
        gemm_nt<<<dim3(32, 32, gc), 256, 0, stream>>>(
            Q + (size_t)h0 * HD, K + (size_t)h0 * HD, Sc, SEQ, SEQ, HD,
            DIM, DIM, SEQ, HD, HD, (long)SEQ * SEQ, QK_SCALE, 1, 0);
        softmax_rows<<<dim3(SEQ, gc), 256, 0, stream>>>(Sc);
        warmup_select<<<dim3(SEQ / 256, gc), 256, 0, stream>>>(Sc, sel0);
        h2o_scan2<<<dim3(gc), 64, 0, stream>>>(Sc, sel0, evct);
        mask_renorm<<<dim3(SEQ - CACHEB, gc), 256, 0, stream>>>(Sc, evct);
        gemm_nt<<<dim3(HD / 64, 32, gc), 256, 0, stream>>>(
            Sc, Vt + (size_t)h0 * HD * SEQ, O + (size_t)h0 * HD, SEQ, HD, SEQ,
            SEQ, SEQ, DIM, (long)SEQ * SEQ, (long)HD * SEQ, HD, 1.f, 0, 1);
    }

    // 9. final projection: out = O @ wo^T
    gemm_nt<<<dim3(32, 32, 1), 256, 0, stream>>>(O, wo, out, SEQ, DIM, DIM,
        DIM, DIM, DIM, 0, 0, 0, 1.f, 0, 0);
}